// Round 5
// baseline (336.439 us; speedup 1.0000x reference)
//
#include <hip/hip_runtime.h>
#include <math.h>

#define B_TOT 2048
#define R_TOT 512
#define D_TOT 256
#define LOG2E 1.4426950408889634f
#define SCALE_C 2.220446049250313e-16f   // 2^-52 exact

typedef float vf4 __attribute__((ext_vector_type(4)));
typedef float vf2 __attribute__((ext_vector_type(2)));

// gated = (1 + m1*e)/(1 + e),  e = exp2(A*x + Bc)
// A = -log2e*kappa*tanh(sign), Bc = -A*th, m1 = 1 - sigmoid(mask)
// Param planes: ppA[r*256+d], ppB[r*256+d], ppM[r*256+d].
// ppM carries 2^-52 folded at d%8==0 so each 8-d rcp group's num/den both
// carry the same scale -> ratio exact.
// Also zeroes y (blocks 0..7) so the separate memset dispatch is dropped.

__global__ void prep_kernel(const float* __restrict__ th,
                            const float* __restrict__ sp,
                            const float* __restrict__ ml,
                            const float* __restrict__ lk,
                            float* __restrict__ pp,
                            float* __restrict__ y) {
    int idx = blockIdx.x * 256 + threadIdx.x;   // r*256 + d
    if (blockIdx.x < (B_TOT / 256)) y[idx] = 0.0f;   // idx < 2048 here
    if (idx >= R_TOT * D_TOT) return;
    float kmul = -LOG2E * __builtin_amdgcn_exp2f(lk[0] * LOG2E);
    float u  = sp[idx];
    float eu = __builtin_amdgcn_exp2f(2.0f * LOG2E * u);
    float t  = 1.0f - 2.0f * __builtin_amdgcn_rcpf(eu + 1.0f);
    float A  = kmul * t;
    float Bc = -A * th[idx];
    float em = __builtin_amdgcn_exp2f(LOG2E * ml[idx]);
    float m1 = __builtin_amdgcn_rcpf(1.0f + em);
    int d = idx & 255;
    pp[idx]                       = A;
    pp[R_TOT * D_TOT + idx]       = Bc;
    pp[2 * R_TOT * D_TOT + idx]   = m1 * (((d & 7) == 0) ? SCALE_C : 1.0f);
}

// ---------------------------------------------------------------------------
// Main: WG = 256 = 4 waves. Block -> 16 rules x 32 batches; wave -> 4 rules
// sequentially for the block's 32 batches. Lane l owns the FULL 8-d group
// d = 8*(l&31)..+7; lane halves (p = l>>5) cover two batch rows per step.
// In-lane 8-way num/den product trees, one rcp per 2 batches.
// Per rule: reload params (6 b128, L1/L2-hit, hidden by TLP), 8 q-iters,
// lgkmcnt-ordered wave-private LDS transpose, lane<32 accumulates w_r*z in
// a register. End: ONE cross-wave combine (single barrier) and ONE
// atomicAdd per (block, batch): 65k atomics total, 32 adds/address
// (round-4's 512 adds/address quadrupled WRITE_SIZE and stalled the pipe).
// grid = (512/16 rules, 2048/32 batches) = 32 x 64 = 2048 blocks.
// ---------------------------------------------------------------------------
__global__ __launch_bounds__(256, 8) void main_kernel(
        const float* __restrict__ x,       // [B_TOT][D_TOT]
        const float* __restrict__ pp,      // 3 planes of [R_TOT][D_TOT]
        const float* __restrict__ head_w,  // [R_TOT]
        const float* __restrict__ head_b,  // [1]
        float*       __restrict__ y) {     // [B_TOT]
    __shared__ float rbuf[4][32][36];      // 18.4 KB; pad 36: 16B-aligned
    __shared__ float wz[4][32];

    const int tid  = threadIdx.x;
    const int lane = tid & 63;
    const int wave = tid >> 6;
    const int col  = lane & 31;            // which 8-d group
    const int p    = lane >> 5;            // batch parity within row pair
    const int b0   = blockIdx.y << 5;            // 32 batches
    const int rbase = (blockIdx.x << 4) + (wave << 2);   // wave's 4 rules

    const vf4 Klo = {SCALE_C, 1.0f, 1.0f, 1.0f};
    const float* xb = x + (size_t)(b0 + p) * D_TOT + (col << 3);

    float acc = 0.0f;                      // lane<32: sum_r w_r * z(b0+lane,r)

    for (int rr = 0; rr < 4; rr++) {
        const int r = rbase + rr;
        // ---- params for this rule: two vf4 per plane, in VGPRs ----
        const float* ppr = pp + r * D_TOT + (col << 3);
        vf4 A0  = *(const vf4*)(ppr);
        vf4 A1  = *(const vf4*)(ppr + 4);
        vf4 Bc0 = *(const vf4*)(ppr + R_TOT * D_TOT);
        vf4 Bc1 = *(const vf4*)(ppr + R_TOT * D_TOT + 4);
        vf4 M0  = *(const vf4*)(ppr + 2 * R_TOT * D_TOT);   // .x has 2^-52
        vf4 M1  = *(const vf4*)(ppr + 2 * R_TOT * D_TOT + 4);

        #pragma unroll
        for (int q = 0; q < 8; q++) {
            // batch rows 4q+p ("A") and 4q+2+p ("C")
            const float* xq = xb + q * (4 * D_TOT);
            vf4 xa0 = *(const vf4*)(xq);
            vf4 xa1 = *(const vf4*)(xq + 4);
            vf4 xc0 = *(const vf4*)(xq + 2 * D_TOT);
            vf4 xc1 = *(const vf4*)(xq + 2 * D_TOT + 4);

            vf4 ta0 = A0 * xa0 + Bc0;          // v_pk_fma_f32
            vf4 ta1 = A1 * xa1 + Bc1;
            vf4 tc0 = A0 * xc0 + Bc0;
            vf4 tc1 = A1 * xc1 + Bc1;

            vf4 ea0, ea1, ec0, ec1;
            ea0.x = __builtin_amdgcn_exp2f(ta0.x);
            ea0.y = __builtin_amdgcn_exp2f(ta0.y);
            ea0.z = __builtin_amdgcn_exp2f(ta0.z);
            ea0.w = __builtin_amdgcn_exp2f(ta0.w);
            ea1.x = __builtin_amdgcn_exp2f(ta1.x);
            ea1.y = __builtin_amdgcn_exp2f(ta1.y);
            ea1.z = __builtin_amdgcn_exp2f(ta1.z);
            ea1.w = __builtin_amdgcn_exp2f(ta1.w);
            ec0.x = __builtin_amdgcn_exp2f(tc0.x);
            ec0.y = __builtin_amdgcn_exp2f(tc0.y);
            ec0.z = __builtin_amdgcn_exp2f(tc0.z);
            ec0.w = __builtin_amdgcn_exp2f(tc0.w);
            ec1.x = __builtin_amdgcn_exp2f(tc1.x);
            ec1.y = __builtin_amdgcn_exp2f(tc1.y);
            ec1.z = __builtin_amdgcn_exp2f(tc1.z);
            ec1.w = __builtin_amdgcn_exp2f(tc1.w);

            // scaled num/den factors (scale on first elem only)
            vf4 na0 = M0 * ea0 + Klo;
            vf4 na1 = M1 * ea1 + 1.0f;
            vf4 da0 = ea0 * Klo + Klo;
            vf4 da1 = ea1 + 1.0f;
            vf4 nc0 = M0 * ec0 + Klo;
            vf4 nc1 = M1 * ec1 + 1.0f;
            vf4 dc0 = ec0 * Klo + Klo;
            vf4 dc1 = ec1 + 1.0f;

            // in-lane 8-way product trees
            vf4 qn_a = na0 * na1;
            vf4 qd_a = da0 * da1;
            vf4 qn_c = nc0 * nc1;
            vf4 qd_c = dc0 * dc1;
            vf2 hn_a = qn_a.lo * qn_a.hi;
            vf2 hd_a = qd_a.lo * qd_a.hi;
            vf2 hn_c = qn_c.lo * qn_c.hi;
            vf2 hd_c = qd_c.lo * qd_c.hi;
            float npA = hn_a.x * hn_a.y;
            float dpA = hd_a.x * hd_a.y;
            float npC = hn_c.x * hn_c.y;
            float dpC = hd_c.x * hd_c.y;

            // one rcp serves both batches: r_b = np_b / dp_b
            float inv = __builtin_amdgcn_rcpf(dpA * dpC);
            float rA  = npA * (dpC * inv);
            float rC  = npC * (dpA * inv);
            rbuf[wave][4 * q + p][col]     = rA;
            rbuf[wave][4 * q + 2 + p][col] = rC;
        }

        // wave-private: order own ds_writes before reads; no block barrier.
        // (in-order DS pipe + LDS alias analysis keep next rule's writes
        //  from passing these reads)
        asm volatile("s_waitcnt lgkmcnt(0)" ::: "memory");

        if (lane < 32) {
            const float* rb2 = &rbuf[wave][lane][0];   // one batch row/lane
            vf4 a0 = *(const vf4*)(rb2)      * *(const vf4*)(rb2 + 4);
            vf4 a1 = *(const vf4*)(rb2 + 8)  * *(const vf4*)(rb2 + 12);
            vf4 a2 = *(const vf4*)(rb2 + 16) * *(const vf4*)(rb2 + 20);
            vf4 a3 = *(const vf4*)(rb2 + 24) * *(const vf4*)(rb2 + 28);
            vf4 m  = (a0 * a1) * (a2 * a3);
            vf2 h  = m.lo * m.hi;
            float z = h.x * h.y;                 // z(b0+lane, r)
            acc += head_w[r] * z;
        }
    }

    // ---- one cross-wave combine, one atomic per (block, batch) ----
    if (lane < 32) wz[wave][lane] = acc;
    __syncthreads();
    if (wave == 0 && lane < 32) {
        float s = wz[0][lane] + wz[1][lane] + wz[2][lane] + wz[3][lane];
        if (blockIdx.x == 0) s += head_b[0];   // bias exactly once per batch
        atomicAdd(&y[b0 + lane], s);
    }
}

extern "C" void kernel_launch(void* const* d_in, const int* in_sizes, int n_in,
                              void* d_out, int out_size, void* d_ws, size_t ws_size,
                              hipStream_t stream) {
    const float* x  = (const float*)d_in[0];
    const float* th = (const float*)d_in[1];
    const float* sp = (const float*)d_in[2];
    const float* ml = (const float*)d_in[3];
    const float* lk = (const float*)d_in[4];
    const float* hw = (const float*)d_in[5];
    const float* hb = (const float*)d_in[6];
    float* y = (float*)d_out;

    float* pp = (float*)d_ws;   // 3 * 512 * 256 floats = 1.5 MB

    prep_kernel<<<R_TOT, 256, 0, stream>>>(th, sp, ml, lk, pp, y);
    dim3 grid(R_TOT / 16, B_TOT / 32, 1);
    main_kernel<<<grid, 256, 0, stream>>>(x, pp, hw, hb, y);
}

// Round 6
// 111.530 us; speedup vs baseline: 3.0166x; 3.0166x over previous
//
#include <hip/hip_runtime.h>
#include <math.h>

#define B_TOT 2048
#define R_TOT 512
#define D_TOT 256
#define LOG2E 1.4426950408889634f
#define SCALE_C 2.220446049250313e-16f   // 2^-52 exact

typedef float vf4 __attribute__((ext_vector_type(4)));
typedef float vf2 __attribute__((ext_vector_type(2)));

// gated = (1 + m1*e)/(1 + e),  e = exp2(A*x + Bc)
// A = -log2e*kappa*tanh(sign), Bc = -A*th, m1 = 1 - sigmoid(mask)
// Param planes: ppA[r*256+d], ppB[r*256+d], ppM[r*256+d].
// ppM carries 2^-52 folded at d%8==0 so each 8-d rcp group's num/den both
// carry the same scale -> ratio exact.
// Also zeroes y (blocks 0..7) so the separate memset dispatch is dropped.

__global__ void prep_kernel(const float* __restrict__ th,
                            const float* __restrict__ sp,
                            const float* __restrict__ ml,
                            const float* __restrict__ lk,
                            float* __restrict__ pp,
                            float* __restrict__ y) {
    int idx = blockIdx.x * 256 + threadIdx.x;   // r*256 + d
    if (blockIdx.x < (B_TOT / 256)) y[idx] = 0.0f;   // idx < 2048 here
    if (idx >= R_TOT * D_TOT) return;
    float kmul = -LOG2E * __builtin_amdgcn_exp2f(lk[0] * LOG2E);
    float u  = sp[idx];
    float eu = __builtin_amdgcn_exp2f(2.0f * LOG2E * u);
    float t  = 1.0f - 2.0f * __builtin_amdgcn_rcpf(eu + 1.0f);
    float A  = kmul * t;
    float Bc = -A * th[idx];
    float em = __builtin_amdgcn_exp2f(LOG2E * ml[idx]);
    float m1 = __builtin_amdgcn_rcpf(1.0f + em);
    int d = idx & 255;
    pp[idx]                       = A;
    pp[R_TOT * D_TOT + idx]       = Bc;
    pp[2 * R_TOT * D_TOT + idx]   = m1 * (((d & 7) == 0) ? SCALE_C : 1.0f);
}

// ---------------------------------------------------------------------------
// Main: WG = 512 = 8 waves. wave -> 1 rule (straight-line, fully unrolled —
// round-5's dynamic rule loop spilled to scratch, 60x HBM traffic, NEVER
// again); WG -> 8 rules x 32 batches. Lane l owns the FULL 8-d group
// d = 8*(l&31)..+7; lane halves (p = l>>5) cover two batch rows per step.
// In-lane 8-way num/den product trees, one rcp per 2 batches.
// 8 q-iters between end-phases (busy 364 cyc/q-iter measured r4) and ONE
// atomicAdd per (block, batch): 64 adds per y address (r2 had 128, r4's 512
// cost +137 cyc/q-iter idle — atomic idle is linear in adds/address).
// LDS 37.9 KB -> 4 blocks/CU x 512 thr = full 2048 thr/CU.
// grid = (512/8 rules, 2048/32 batches) = 64 x 64.
// ---------------------------------------------------------------------------
__global__ __launch_bounds__(512, 4) void main_kernel(
        const float* __restrict__ x,       // [B_TOT][D_TOT]
        const float* __restrict__ pp,      // 3 planes of [R_TOT][D_TOT]
        const float* __restrict__ head_w,  // [R_TOT]
        const float* __restrict__ head_b,  // [1]
        float*       __restrict__ y) {     // [B_TOT]
    __shared__ float rbuf[8][32][36];      // 36.9 KB; pad 36: 16B-aligned
    __shared__ float wz[8][32];

    const int tid  = threadIdx.x;
    const int lane = tid & 63;
    const int wave = tid >> 6;             // 0..7
    const int col  = lane & 31;            // which 8-d group
    const int p    = lane >> 5;            // batch parity within row pair
    const int r0   = (blockIdx.x << 3) + wave;   // this wave's rule
    const int b0   = blockIdx.y << 5;            // 32 batches

    // ---- params: 8 d's per lane = two vf4 per plane, held in VGPRs ----
    const float* ppr = pp + r0 * D_TOT + (col << 3);
    vf4 A0  = *(const vf4*)(ppr);
    vf4 A1  = *(const vf4*)(ppr + 4);
    vf4 Bc0 = *(const vf4*)(ppr + R_TOT * D_TOT);
    vf4 Bc1 = *(const vf4*)(ppr + R_TOT * D_TOT + 4);
    vf4 M0  = *(const vf4*)(ppr + 2 * R_TOT * D_TOT);     // .x carries 2^-52
    vf4 M1  = *(const vf4*)(ppr + 2 * R_TOT * D_TOT + 4);
    const vf4 Klo = {SCALE_C, 1.0f, 1.0f, 1.0f};

    const float* xb = x + (size_t)(b0 + p) * D_TOT + (col << 3);

    #pragma unroll
    for (int q = 0; q < 8; q++) {
        // batch rows 4q+p ("A") and 4q+2+p ("C")
        const float* xq = xb + q * (4 * D_TOT);
        vf4 xa0 = *(const vf4*)(xq);
        vf4 xa1 = *(const vf4*)(xq + 4);
        vf4 xc0 = *(const vf4*)(xq + 2 * D_TOT);
        vf4 xc1 = *(const vf4*)(xq + 2 * D_TOT + 4);

        vf4 ta0 = A0 * xa0 + Bc0;          // v_pk_fma_f32
        vf4 ta1 = A1 * xa1 + Bc1;
        vf4 tc0 = A0 * xc0 + Bc0;
        vf4 tc1 = A1 * xc1 + Bc1;

        vf4 ea0, ea1, ec0, ec1;
        ea0.x = __builtin_amdgcn_exp2f(ta0.x);
        ea0.y = __builtin_amdgcn_exp2f(ta0.y);
        ea0.z = __builtin_amdgcn_exp2f(ta0.z);
        ea0.w = __builtin_amdgcn_exp2f(ta0.w);
        ea1.x = __builtin_amdgcn_exp2f(ta1.x);
        ea1.y = __builtin_amdgcn_exp2f(ta1.y);
        ea1.z = __builtin_amdgcn_exp2f(ta1.z);
        ea1.w = __builtin_amdgcn_exp2f(ta1.w);
        ec0.x = __builtin_amdgcn_exp2f(tc0.x);
        ec0.y = __builtin_amdgcn_exp2f(tc0.y);
        ec0.z = __builtin_amdgcn_exp2f(tc0.z);
        ec0.w = __builtin_amdgcn_exp2f(tc0.w);
        ec1.x = __builtin_amdgcn_exp2f(tc1.x);
        ec1.y = __builtin_amdgcn_exp2f(tc1.y);
        ec1.z = __builtin_amdgcn_exp2f(tc1.z);
        ec1.w = __builtin_amdgcn_exp2f(tc1.w);

        // scaled numerator / denominator factors (scale on first elem only)
        vf4 na0 = M0 * ea0 + Klo;
        vf4 na1 = M1 * ea1 + 1.0f;
        vf4 da0 = ea0 * Klo + Klo;
        vf4 da1 = ea1 + 1.0f;
        vf4 nc0 = M0 * ec0 + Klo;
        vf4 nc1 = M1 * ec1 + 1.0f;
        vf4 dc0 = ec0 * Klo + Klo;
        vf4 dc1 = ec1 + 1.0f;

        // in-lane 8-way product trees
        vf4 qn_a = na0 * na1;
        vf4 qd_a = da0 * da1;
        vf4 qn_c = nc0 * nc1;
        vf4 qd_c = dc0 * dc1;
        vf2 hn_a = qn_a.lo * qn_a.hi;
        vf2 hd_a = qd_a.lo * qd_a.hi;
        vf2 hn_c = qn_c.lo * qn_c.hi;
        vf2 hd_c = qd_c.lo * qd_c.hi;
        float npA = hn_a.x * hn_a.y;
        float dpA = hd_a.x * hd_a.y;
        float npC = hn_c.x * hn_c.y;
        float dpC = hd_c.x * hd_c.y;

        // one rcp serves both batches: r_b = np_b / dp_b
        float inv = __builtin_amdgcn_rcpf(dpA * dpC);
        float rA  = npA * (dpC * inv);
        float rC  = npC * (dpA * inv);
        rbuf[wave][4 * q + p][col]     = rA;
        rbuf[wave][4 * q + 2 + p][col] = rC;
    }

    // ---- end-phase: per-batch product over the 32 ratio columns ----
    __syncthreads();

    if (lane < 32) {
        const float* rb2 = &rbuf[wave][lane][0];   // one batch row per lane
        vf4 a0 = *(const vf4*)(rb2)      * *(const vf4*)(rb2 + 4);
        vf4 a1 = *(const vf4*)(rb2 + 8)  * *(const vf4*)(rb2 + 12);
        vf4 a2 = *(const vf4*)(rb2 + 16) * *(const vf4*)(rb2 + 20);
        vf4 a3 = *(const vf4*)(rb2 + 24) * *(const vf4*)(rb2 + 28);
        vf4 m  = (a0 * a1) * (a2 * a3);
        vf2 h  = m.lo * m.hi;
        float z = h.x * h.y;                 // z(b0+lane, r0)
        wz[wave][lane] = head_w[r0] * z;
    }
    __syncthreads();

    if (wave == 0 && lane < 32) {
        float s = (wz[0][lane] + wz[1][lane]) + (wz[2][lane] + wz[3][lane]);
        float t2 = (wz[4][lane] + wz[5][lane]) + (wz[6][lane] + wz[7][lane]);
        s += t2;
        if (blockIdx.x == 0) s += head_b[0];   // bias exactly once per batch
        atomicAdd(&y[b0 + lane], s);
    }
}

extern "C" void kernel_launch(void* const* d_in, const int* in_sizes, int n_in,
                              void* d_out, int out_size, void* d_ws, size_t ws_size,
                              hipStream_t stream) {
    const float* x  = (const float*)d_in[0];
    const float* th = (const float*)d_in[1];
    const float* sp = (const float*)d_in[2];
    const float* ml = (const float*)d_in[3];
    const float* lk = (const float*)d_in[4];
    const float* hw = (const float*)d_in[5];
    const float* hb = (const float*)d_in[6];
    float* y = (float*)d_out;

    float* pp = (float*)d_ws;   // 3 * 512 * 256 floats = 1.5 MB

    prep_kernel<<<R_TOT, 256, 0, stream>>>(th, sp, ml, lk, pp, y);
    dim3 grid(R_TOT / 8, B_TOT / 32, 1);
    main_kernel<<<grid, 512, 0, stream>>>(x, pp, hw, hb, y);
}

// Round 7
// 109.872 us; speedup vs baseline: 3.0621x; 1.0151x over previous
//
#include <hip/hip_runtime.h>
#include <math.h>

#define B_TOT 2048
#define R_TOT 512
#define D_TOT 256
#define LOG2E 1.4426950408889634f
#define SCALE_C 2.220446049250313e-16f   // 2^-52 exact

typedef float vf4 __attribute__((ext_vector_type(4)));
typedef float vf2 __attribute__((ext_vector_type(2)));

// gated = (1 + m1*e)/(1 + e),  e = exp2(A*x + Bc)
// A = -log2e*kappa*tanh(sign), Bc = -A*th, m1 = 1 - sigmoid(mask)
// Param planes: ppA[r*256+d], ppB[r*256+d], ppM[r*256+d].
// ppM carries 2^-52 folded at d%8==0 so each 8-d rcp group's num/den both
// carry the same scale -> ratio exact.
// Also zeroes y (blocks 0..7) so the separate memset dispatch is dropped.

__global__ void prep_kernel(const float* __restrict__ th,
                            const float* __restrict__ sp,
                            const float* __restrict__ ml,
                            const float* __restrict__ lk,
                            float* __restrict__ pp,
                            float* __restrict__ y) {
    int idx = blockIdx.x * 256 + threadIdx.x;   // r*256 + d
    if (blockIdx.x < (B_TOT / 256)) y[idx] = 0.0f;   // idx < 2048 here
    if (idx >= R_TOT * D_TOT) return;
    float kmul = -LOG2E * __builtin_amdgcn_exp2f(lk[0] * LOG2E);
    float u  = sp[idx];
    float eu = __builtin_amdgcn_exp2f(2.0f * LOG2E * u);
    float t  = 1.0f - 2.0f * __builtin_amdgcn_rcpf(eu + 1.0f);
    float A  = kmul * t;
    float Bc = -A * th[idx];
    float em = __builtin_amdgcn_exp2f(LOG2E * ml[idx]);
    float m1 = __builtin_amdgcn_rcpf(1.0f + em);
    int d = idx & 255;
    pp[idx]                       = A;
    pp[R_TOT * D_TOT + idx]       = Bc;
    pp[2 * R_TOT * D_TOT + idx]   = m1 * (((d & 7) == 0) ? SCALE_C : 1.0f);
}

// ---------------------------------------------------------------------------
// Main: WG = 512 = 8 waves. wave -> 1 rule (straight-line, fully unrolled —
// round-5's dynamic rule loop spilled to scratch, 60x HBM traffic, NEVER
// again); WG -> 8 rules x 32 batches. Lane l owns the FULL 8-d group
// d = 8*(l&31)..+7; lane halves (p = l>>5) cover two batch rows per step.
// In-lane 8-way num/den product trees, one rcp per 2 batches.
// NEW (r7): explicit 1-deep software pipeline on the x loads — prefetch
// q+1's 4 vf4 before computing q. Round-6 ran at VGPR=32: the compiler
// could not keep any loads in flight, leaving ~130 cyc/q-iter of load-wait
// idle (27% of wall) that 5.5 waves/SIMD TLP couldn't cover. Compile-time
// rotation only (no dynamic indexing -> no scratch, r5 lesson).
// One atomicAdd per (block, batch): 64 adds per y address.
// LDS 37.9 KB -> 4 blocks/CU x 512 thr = full 2048 thr/CU.
// grid = (512/8 rules, 2048/32 batches) = 64 x 64.
// ---------------------------------------------------------------------------
__global__ __launch_bounds__(512, 4) void main_kernel(
        const float* __restrict__ x,       // [B_TOT][D_TOT]
        const float* __restrict__ pp,      // 3 planes of [R_TOT][D_TOT]
        const float* __restrict__ head_w,  // [R_TOT]
        const float* __restrict__ head_b,  // [1]
        float*       __restrict__ y) {     // [B_TOT]
    __shared__ float rbuf[8][32][36];      // 36.9 KB; pad 36: 16B-aligned
    __shared__ float wz[8][32];

    const int tid  = threadIdx.x;
    const int lane = tid & 63;
    const int wave = tid >> 6;             // 0..7
    const int col  = lane & 31;            // which 8-d group
    const int p    = lane >> 5;            // batch parity within row pair
    const int r0   = (blockIdx.x << 3) + wave;   // this wave's rule
    const int b0   = blockIdx.y << 5;            // 32 batches

    // ---- params: 8 d's per lane = two vf4 per plane, held in VGPRs ----
    const float* ppr = pp + r0 * D_TOT + (col << 3);
    vf4 A0  = *(const vf4*)(ppr);
    vf4 A1  = *(const vf4*)(ppr + 4);
    vf4 Bc0 = *(const vf4*)(ppr + R_TOT * D_TOT);
    vf4 Bc1 = *(const vf4*)(ppr + R_TOT * D_TOT + 4);
    vf4 M0  = *(const vf4*)(ppr + 2 * R_TOT * D_TOT);     // .x carries 2^-52
    vf4 M1  = *(const vf4*)(ppr + 2 * R_TOT * D_TOT + 4);
    const vf4 Klo = {SCALE_C, 1.0f, 1.0f, 1.0f};

    const float* xb = x + (size_t)(b0 + p) * D_TOT + (col << 3);

    // ---- software pipeline: stage q=0 loads ----
    vf4 xa0 = *(const vf4*)(xb);
    vf4 xa1 = *(const vf4*)(xb + 4);
    vf4 xc0 = *(const vf4*)(xb + 2 * D_TOT);
    vf4 xc1 = *(const vf4*)(xb + 2 * D_TOT + 4);

    #pragma unroll
    for (int q = 0; q < 8; q++) {
        // prefetch q+1 (compile-time guarded; rotation is static)
        vf4 ya0, ya1, yc0, yc1;
        if (q < 7) {
            const float* xn = xb + (q + 1) * (4 * D_TOT);
            ya0 = *(const vf4*)(xn);
            ya1 = *(const vf4*)(xn + 4);
            yc0 = *(const vf4*)(xn + 2 * D_TOT);
            yc1 = *(const vf4*)(xn + 2 * D_TOT + 4);
        } else {
            ya0 = xa0; ya1 = xa1; yc0 = xc0; yc1 = xc1;
        }

        vf4 ta0 = A0 * xa0 + Bc0;          // v_pk_fma_f32
        vf4 ta1 = A1 * xa1 + Bc1;
        vf4 tc0 = A0 * xc0 + Bc0;
        vf4 tc1 = A1 * xc1 + Bc1;

        vf4 ea0, ea1, ec0, ec1;
        ea0.x = __builtin_amdgcn_exp2f(ta0.x);
        ea0.y = __builtin_amdgcn_exp2f(ta0.y);
        ea0.z = __builtin_amdgcn_exp2f(ta0.z);
        ea0.w = __builtin_amdgcn_exp2f(ta0.w);
        ea1.x = __builtin_amdgcn_exp2f(ta1.x);
        ea1.y = __builtin_amdgcn_exp2f(ta1.y);
        ea1.z = __builtin_amdgcn_exp2f(ta1.z);
        ea1.w = __builtin_amdgcn_exp2f(ta1.w);
        ec0.x = __builtin_amdgcn_exp2f(tc0.x);
        ec0.y = __builtin_amdgcn_exp2f(tc0.y);
        ec0.z = __builtin_amdgcn_exp2f(tc0.z);
        ec0.w = __builtin_amdgcn_exp2f(tc0.w);
        ec1.x = __builtin_amdgcn_exp2f(tc1.x);
        ec1.y = __builtin_amdgcn_exp2f(tc1.y);
        ec1.z = __builtin_amdgcn_exp2f(tc1.z);
        ec1.w = __builtin_amdgcn_exp2f(tc1.w);

        // scaled numerator / denominator factors (scale on first elem only)
        vf4 na0 = M0 * ea0 + Klo;
        vf4 na1 = M1 * ea1 + 1.0f;
        vf4 da0 = ea0 * Klo + Klo;
        vf4 da1 = ea1 + 1.0f;
        vf4 nc0 = M0 * ec0 + Klo;
        vf4 nc1 = M1 * ec1 + 1.0f;
        vf4 dc0 = ec0 * Klo + Klo;
        vf4 dc1 = ec1 + 1.0f;

        // in-lane 8-way product trees
        vf4 qn_a = na0 * na1;
        vf4 qd_a = da0 * da1;
        vf4 qn_c = nc0 * nc1;
        vf4 qd_c = dc0 * dc1;
        vf2 hn_a = qn_a.lo * qn_a.hi;
        vf2 hd_a = qd_a.lo * qd_a.hi;
        vf2 hn_c = qn_c.lo * qn_c.hi;
        vf2 hd_c = qd_c.lo * qd_c.hi;
        float npA = hn_a.x * hn_a.y;
        float dpA = hd_a.x * hd_a.y;
        float npC = hn_c.x * hn_c.y;
        float dpC = hd_c.x * hd_c.y;

        // one rcp serves both batches: r_b = np_b / dp_b
        float inv = __builtin_amdgcn_rcpf(dpA * dpC);
        float rA  = npA * (dpC * inv);
        float rC  = npC * (dpA * inv);
        rbuf[wave][4 * q + p][col]     = rA;
        rbuf[wave][4 * q + 2 + p][col] = rC;

        // rotate pipeline registers (static)
        xa0 = ya0; xa1 = ya1; xc0 = yc0; xc1 = yc1;
    }

    // ---- end-phase: per-batch product over the 32 ratio columns ----
    __syncthreads();

    if (lane < 32) {
        const float* rb2 = &rbuf[wave][lane][0];   // one batch row per lane
        vf4 a0 = *(const vf4*)(rb2)      * *(const vf4*)(rb2 + 4);
        vf4 a1 = *(const vf4*)(rb2 + 8)  * *(const vf4*)(rb2 + 12);
        vf4 a2 = *(const vf4*)(rb2 + 16) * *(const vf4*)(rb2 + 20);
        vf4 a3 = *(const vf4*)(rb2 + 24) * *(const vf4*)(rb2 + 28);
        vf4 m  = (a0 * a1) * (a2 * a3);
        vf2 h  = m.lo * m.hi;
        float z = h.x * h.y;                 // z(b0+lane, r0)
        wz[wave][lane] = head_w[r0] * z;
    }
    __syncthreads();

    if (wave == 0 && lane < 32) {
        float s = (wz[0][lane] + wz[1][lane]) + (wz[2][lane] + wz[3][lane]);
        float t2 = (wz[4][lane] + wz[5][lane]) + (wz[6][lane] + wz[7][lane]);
        s += t2;
        if (blockIdx.x == 0) s += head_b[0];   // bias exactly once per batch
        atomicAdd(&y[b0 + lane], s);
    }
}

extern "C" void kernel_launch(void* const* d_in, const int* in_sizes, int n_in,
                              void* d_out, int out_size, void* d_ws, size_t ws_size,
                              hipStream_t stream) {
    const float* x  = (const float*)d_in[0];
    const float* th = (const float*)d_in[1];
    const float* sp = (const float*)d_in[2];
    const float* ml = (const float*)d_in[3];
    const float* lk = (const float*)d_in[4];
    const float* hw = (const float*)d_in[5];
    const float* hb = (const float*)d_in[6];
    float* y = (float*)d_out;

    float* pp = (float*)d_ws;   // 3 * 512 * 256 floats = 1.5 MB

    prep_kernel<<<R_TOT, 256, 0, stream>>>(th, sp, ml, lk, pp, y);
    dim3 grid(R_TOT / 8, B_TOT / 32, 1);
    main_kernel<<<grid, 512, 0, stream>>>(x, pp, hw, hb, y);
}